// Round 4
// baseline (662.017 us; speedup 1.0000x reference)
//
#include <hip/hip_runtime.h>
#include <hip/hip_bf16.h>
#include <cstdint>
#include <cstddef>

// B=2,S=2048 -> N=4096 tokens, H=1024, F=2048, E=8, top-2 routing.
// Inputs/outputs fp32 (detected at runtime; bf16 path kept for robustness).
// GEMM compute: bf16 MFMA (16x16x32), fp32 accumulate.
#define N_TOK 4096
#define H_DIM 1024
#define F_DIM 2048
#define E_NUM 8
#define RCAP 9216  // 2*N + E*127 rounded up to 128

typedef __attribute__((ext_vector_type(8))) short bf16x8;
typedef __attribute__((ext_vector_type(4))) float f32x4;

__device__ __forceinline__ float b2f(uint16_t u) {
  return __uint_as_float(((uint32_t)u) << 16);
}
__device__ __forceinline__ uint16_t f2b(float f) {
  uint32_t x = __float_as_uint(f);
  uint32_t r = (x + 0x7fffu + ((x >> 16) & 1u)) >> 16;
  return (uint16_t)r;
}

__device__ __forceinline__ void gl2lds16(const void* g, void* l) {
  __builtin_amdgcn_global_load_lds(
      (const __attribute__((address_space(1))) uint32_t*)g,
      (__attribute__((address_space(3))) uint32_t*)l, 16, 0, 0);
}

// ---------------- input dtype detection ----------------
__global__ __launch_bounds__(256) void detect_kernel(
    const uint16_t* __restrict__ x, int* __restrict__ flag) {
  __shared__ int cnt;
  if (threadIdx.x == 0) cnt = 0;
  __syncthreads();
  int ok = 0;
  for (int j = 0; j < 16; ++j) {
    uint16_t u = x[threadIdx.x * 16 + j];
    int e = (u >> 7) & 0xff;
    ok += (u == 0 || (e >= 96 && e <= 143)) ? 1 : 0;
  }
  atomicAdd(&cnt, ok);
  __syncthreads();
  if (threadIdx.x == 0) *flag = (cnt >= 3700) ? 1 : 0;  // 1 = bf16 inputs
}

// ---------------- router: fp32 logits (native-dtype reads), top-2 ----------
__global__ __launch_bounds__(256) void router_kernel(
    const void* __restrict__ xraw, const void* __restrict__ gwraw,
    const int* __restrict__ flag, void* __restrict__ dout,
    int* __restrict__ top_i, float* __restrict__ top_w,
    int* __restrict__ counts) {
  int fl = *flag;
  int wave = threadIdx.x >> 6, lane = threadIdx.x & 63;
  int t = blockIdx.x * 4 + wave;  // one wave per token
  float xv[16];
  if (fl) {
    const uint16_t* xr = (const uint16_t*)xraw + (size_t)t * H_DIM + lane * 16;
    uint4 a = *(const uint4*)xr;
    uint4 b = *(const uint4*)(xr + 8);
    uint32_t w[8] = {a.x, a.y, a.z, a.w, b.x, b.y, b.z, b.w};
    for (int j = 0; j < 8; ++j) {
      xv[2 * j] = b2f((uint16_t)(w[j] & 0xffff));
      xv[2 * j + 1] = b2f((uint16_t)(w[j] >> 16));
    }
  } else {
    const float* xr = (const float*)xraw + (size_t)t * H_DIM + lane * 16;
    for (int j = 0; j < 4; ++j) {
      float4 v = ((const float4*)xr)[j];
      xv[4 * j] = v.x; xv[4 * j + 1] = v.y;
      xv[4 * j + 2] = v.z; xv[4 * j + 3] = v.w;
    }
  }
  float acc[E_NUM];
  for (int e = 0; e < E_NUM; ++e) {
    float s = 0.f;
    if (fl) {
      const uint16_t* gr =
          (const uint16_t*)gwraw + (size_t)e * H_DIM + lane * 16;
      uint4 a = *(const uint4*)gr;
      uint4 b = *(const uint4*)(gr + 8);
      uint32_t w[8] = {a.x, a.y, a.z, a.w, b.x, b.y, b.z, b.w};
      for (int j = 0; j < 8; ++j) {
        s += xv[2 * j] * b2f((uint16_t)(w[j] & 0xffff));
        s += xv[2 * j + 1] * b2f((uint16_t)(w[j] >> 16));
      }
    } else {
      const float* gr = (const float*)gwraw + (size_t)e * H_DIM + lane * 16;
      for (int j = 0; j < 4; ++j) {
        float4 v = ((const float4*)gr)[j];
        s += xv[4 * j] * v.x + xv[4 * j + 1] * v.y + xv[4 * j + 2] * v.z +
             xv[4 * j + 3] * v.w;
      }
    }
    acc[e] = s;
  }
  for (int off = 32; off >= 1; off >>= 1)
    for (int e = 0; e < E_NUM; ++e)
      acc[e] += __shfl_xor(acc[e], off, 64);
  if (lane < E_NUM) {
    size_t idx = (size_t)N_TOK * H_DIM + (size_t)t * E_NUM + lane;
    if (fl)
      ((uint16_t*)dout)[idx] = f2b(acc[lane]);
    else
      ((float*)dout)[idx] = acc[lane];
  }
  if (lane == 0) {
    int b0 = 0;
    float v0 = acc[0];
    for (int e = 1; e < E_NUM; ++e)
      if (acc[e] > v0) { v0 = acc[e]; b0 = e; }
    int b1 = (b0 == 0) ? 1 : 0;
    float v1 = acc[b1];
    for (int e = 0; e < E_NUM; ++e)
      if (e != b0 && acc[e] > v1) { v1 = acc[e]; b1 = e; }
    float w0 = 1.f / (1.f + expf(v1 - v0));  // top-2 renorm == 2-way softmax
    float w1 = 1.f - w0;
    top_i[2 * t] = b0; top_i[2 * t + 1] = b1;
    top_w[2 * t] = w0; top_w[2 * t + 1] = w1;
    atomicAdd(&counts[b0], 1);
    atomicAdd(&counts[b1], 1);
  }
}

// ---------------- per-expert bases (128-row padded) ----------------
__global__ void offsets_kernel(const int* __restrict__ counts,
                               int* __restrict__ bases, int* __restrict__ cursor) {
  if (threadIdx.x == 0 && blockIdx.x == 0) {
    int b = 0;
    for (int e = 0; e < E_NUM; ++e) {
      bases[e] = b;
      cursor[e] = b;
      b += (counts[e] + 127) & ~127;
    }
  }
}

// ---------------- gather tokens -> contiguous bf16 rows (canonicalize) ------
__global__ __launch_bounds__(256) void gather_kernel(
    const void* __restrict__ xraw, const int* __restrict__ flag,
    const int* __restrict__ top_i, const float* __restrict__ top_w,
    int* __restrict__ cursor, int* __restrict__ row_token,
    float* __restrict__ row_weight, uint16_t* __restrict__ Xg) {
  int t = blockIdx.x;
  __shared__ int rs[2];
  if (threadIdx.x < 2) {
    int e = top_i[2 * t + threadIdx.x];
    int r = atomicAdd(&cursor[e], 1);
    row_token[r] = t;
    row_weight[r] = top_w[2 * t + threadIdx.x];
    rs[threadIdx.x] = r;
  }
  __syncthreads();
  uint2 v;
  if (*flag) {
    v = ((const uint2*)((const uint16_t*)xraw + (size_t)t * H_DIM))[threadIdx.x];
  } else {
    float4 f =
        ((const float4*)((const float*)xraw + (size_t)t * H_DIM))[threadIdx.x];
    v.x = (uint32_t)f2b(f.x) | ((uint32_t)f2b(f.y) << 16);
    v.y = (uint32_t)f2b(f.z) | ((uint32_t)f2b(f.w) << 16);
  }
  ((uint2*)(Xg + (size_t)rs[0] * H_DIM))[threadIdx.x] = v;
  ((uint2*)(Xg + (size_t)rs[1] * H_DIM))[threadIdx.x] = v;
}

// ------------- weight transpose [E][K][N] -> [E][N][K], canonicalize bf16 ---
__global__ __launch_bounds__(256) void transpose_kernel(
    const void* __restrict__ W, const int* __restrict__ flag,
    uint16_t* __restrict__ Wt, int K, int N) {
  int e = blockIdx.z;
  int n0 = blockIdx.x * 64, k0 = blockIdx.y * 64;
  __shared__ __align__(16) uint16_t tile[64][72];
  size_t ebase = (size_t)e * K * N;
  uint16_t* Wout = Wt + ebase;
  int fl = *flag;
  int r = threadIdx.x >> 3;
  int c = (threadIdx.x & 7) * 8;
  if (fl) {
    const uint16_t* Win = (const uint16_t*)W + ebase;
    for (int it = 0; it < 2; ++it) {
      int row = r + it * 32;
      uint4 v = *(const uint4*)(Win + (size_t)(k0 + row) * N + n0 + c);
      *(uint4*)&tile[row][c] = v;
    }
  } else {
    const float* Win = (const float*)W + ebase;
    for (int it = 0; it < 2; ++it) {
      int row = r + it * 32;
      const float* p = Win + (size_t)(k0 + row) * N + n0 + c;
      float4 a = ((const float4*)p)[0];
      float4 b = ((const float4*)p)[1];
      uint16_t* tp = &tile[row][c];
      tp[0] = f2b(a.x); tp[1] = f2b(a.y); tp[2] = f2b(a.z); tp[3] = f2b(a.w);
      tp[4] = f2b(b.x); tp[5] = f2b(b.y); tp[6] = f2b(b.z); tp[7] = f2b(b.w);
    }
  }
  __syncthreads();
  for (int it = 0; it < 2; ++it) {
    int n = r + it * 32;
    uint4 o;
    o.x = (uint32_t)tile[c + 0][n] | ((uint32_t)tile[c + 1][n] << 16);
    o.y = (uint32_t)tile[c + 2][n] | ((uint32_t)tile[c + 3][n] << 16);
    o.z = (uint32_t)tile[c + 4][n] | ((uint32_t)tile[c + 5][n] << 16);
    o.w = (uint32_t)tile[c + 6][n] | ((uint32_t)tile[c + 7][n] << 16);
    *(uint4*)(Wout + (size_t)(n0 + n) * K + k0 + c) = o;
  }
}

// ---------------- MFMA GEMM, 128x128 tile, BK=32 -------
// MODE 0: phi = acc + bias; MODE 1: phi = silu(acc+bias)*phi;
// MODE 2: atomicAdd(out_acc[token] += w * (acc + bias))
template <int MODE>
__global__ __launch_bounds__(256, 2) void gemm_moe(
    const uint16_t* __restrict__ Aall, int lda,
    const uint16_t* __restrict__ Btall, const void* __restrict__ biasRaw,
    const int* __restrict__ flag, int N, int K,
    const int* __restrict__ counts, const int* __restrict__ bases,
    uint16_t* __restrict__ phi,
    const int* __restrict__ row_token, const float* __restrict__ row_weight,
    float* __restrict__ out_acc) {
  int e = blockIdx.z;
  int cnt = counts[e];
  int m0 = blockIdx.y * 128;
  if (m0 >= cnt) return;
  int n0 = blockIdx.x * 128;
  int base = bases[e];
  const uint16_t* A = Aall + (size_t)base * lda;
  const uint16_t* Bt = Btall + (size_t)e * (size_t)N * K;

  __shared__ __align__(16) uint16_t lA[128 * 32];
  __shared__ __align__(16) uint16_t lB[128 * 32];

  int tid = threadIdx.x;
  int wave = tid >> 6, lane = tid & 63;
  int wm = wave >> 1, wn = wave & 1;
  int q = lane >> 4, mr = lane & 15;

  f32x4 acc[4][4] = {};

  for (int k0 = 0; k0 < K; k0 += 32) {
    __syncthreads();
    for (int i = 0; i < 2; ++i) {
      int off = wave * 2048 + i * 1024 + lane * 16;
      int row = off >> 6, inrow = off & 63;
      gl2lds16((const char*)A + ((size_t)(m0 + row) * lda + k0) * 2 + inrow,
               (char*)lA + wave * 2048 + i * 1024);
      gl2lds16((const char*)Bt + ((size_t)(n0 + row) * K + k0) * 2 + inrow,
               (char*)lB + wave * 2048 + i * 1024);
    }
    __syncthreads();
    bf16x8 af[4], bfr[4];
    for (int mt = 0; mt < 4; ++mt)
      af[mt] = *(const bf16x8*)((const char*)lA +
                                (wm * 64 + mt * 16 + mr) * 64 + q * 16);
    for (int nt = 0; nt < 4; ++nt)
      bfr[nt] = *(const bf16x8*)((const char*)lB +
                                 (wn * 64 + nt * 16 + mr) * 64 + q * 16);
    for (int mt = 0; mt < 4; ++mt)
      for (int nt = 0; nt < 4; ++nt)
        acc[mt][nt] = __builtin_amdgcn_mfma_f32_16x16x32_bf16(
            af[mt], bfr[nt], acc[mt][nt], 0, 0, 0);
  }

  int fl = *flag;
  int rbase = m0 + wm * 64;
  int cbase = n0 + wn * 64;
  for (int nt = 0; nt < 4; ++nt) {
    int col = cbase + nt * 16 + mr;
    float bv = fl ? b2f(((const uint16_t*)biasRaw)[(size_t)e * N + col])
                  : ((const float*)biasRaw)[(size_t)e * N + col];
    for (int mt = 0; mt < 4; ++mt) {
      int r0 = rbase + mt * 16 + q * 4;
      for (int rg = 0; rg < 4; ++rg) {
        int row = r0 + rg;
        float v = acc[mt][nt][rg] + bv;
        if (MODE == 0) {
          phi[(size_t)(base + row) * N + col] = f2b(v);
        } else if (MODE == 1) {
          size_t idx = (size_t)(base + row) * N + col;
          float u = b2f(phi[idx]);
          float s = v / (1.f + expf(-v));
          phi[idx] = f2b(s * u);
        } else {
          if (row < cnt) {
            int tkn = row_token[base + row];
            float w = row_weight[base + row];
            atomicAdd(out_acc + (size_t)tkn * N + col, w * v);
          }
        }
      }
    }
  }
}

// ---------------- fp32 accumulator -> output (dtype per flag) ---------------
__global__ __launch_bounds__(256) void out_convert(
    const float* __restrict__ acc, const int* __restrict__ flag,
    void* __restrict__ out) {
  int i = blockIdx.x * 256 + threadIdx.x;
  float4 v = ((const float4*)acc)[i];
  if (*flag) {
    uint2 o;
    o.x = (uint32_t)f2b(v.x) | ((uint32_t)f2b(v.y) << 16);
    o.y = (uint32_t)f2b(v.z) | ((uint32_t)f2b(v.w) << 16);
    ((uint2*)out)[i] = o;
  } else {
    ((float4*)out)[i] = v;
  }
}

extern "C" void kernel_launch(void* const* d_in, const int* in_sizes, int n_in,
                              void* d_out, int out_size, void* d_ws, size_t ws_size,
                              hipStream_t stream) {
  const void* x = d_in[0];
  const void* gw = d_in[1];
  const void* w_up = d_in[2];
  const void* w_gate = d_in[3];
  const void* w_down = d_in[4];
  const void* b_up = d_in[5];
  const void* b_gate = d_in[6];
  const void* b_down = d_in[7];

  char* ws = (char*)d_ws;
  size_t off = 0;
  auto alloc = [&](size_t bytes) -> void* {
    void* p = ws + off;
    off += (bytes + 255) & ~(size_t)255;
    return p;
  };
  int* counts = (int*)alloc(32);
  int* bases = (int*)alloc(32);
  int* cursor = (int*)alloc(32);
  int* flag = (int*)alloc(32);
  int* top_i = (int*)alloc(sizeof(int) * N_TOK * 2);
  float* top_w = (float*)alloc(sizeof(float) * N_TOK * 2);
  int* row_token = (int*)alloc(sizeof(int) * RCAP);
  float* row_weight = (float*)alloc(sizeof(float) * RCAP);
  uint16_t* Xg = (uint16_t*)alloc((size_t)RCAP * H_DIM * 2);
  uint16_t* phi = (uint16_t*)alloc((size_t)RCAP * F_DIM * 2);
  uint16_t* Wt = (uint16_t*)alloc((size_t)E_NUM * H_DIM * F_DIM * 2);
  float* out_acc = (float*)alloc((size_t)N_TOK * H_DIM * sizeof(float));

  hipMemsetAsync(counts, 0, 32, stream);
  hipMemsetAsync(out_acc, 0, (size_t)N_TOK * H_DIM * sizeof(float), stream);

  detect_kernel<<<1, 256, 0, stream>>>((const uint16_t*)x, flag);
  router_kernel<<<N_TOK / 4, 256, 0, stream>>>(x, gw, flag, d_out, top_i,
                                               top_w, counts);
  offsets_kernel<<<1, 64, 0, stream>>>(counts, bases, cursor);
  gather_kernel<<<N_TOK, 256, 0, stream>>>(x, flag, top_i, top_w, cursor,
                                           row_token, row_weight, Xg);

  transpose_kernel<<<dim3(F_DIM / 64, H_DIM / 64, E_NUM), 256, 0, stream>>>(
      w_up, flag, Wt, H_DIM, F_DIM);
  gemm_moe<0><<<dim3(F_DIM / 128, 32, E_NUM), 256, 0, stream>>>(
      Xg, H_DIM, Wt, b_up, flag, F_DIM, H_DIM, counts, bases, phi, row_token,
      row_weight, out_acc);
  transpose_kernel<<<dim3(F_DIM / 64, H_DIM / 64, E_NUM), 256, 0, stream>>>(
      w_gate, flag, Wt, H_DIM, F_DIM);
  gemm_moe<1><<<dim3(F_DIM / 128, 32, E_NUM), 256, 0, stream>>>(
      Xg, H_DIM, Wt, b_gate, flag, F_DIM, H_DIM, counts, bases, phi, row_token,
      row_weight, out_acc);
  transpose_kernel<<<dim3(H_DIM / 64, F_DIM / 64, E_NUM), 256, 0, stream>>>(
      w_down, flag, Wt, F_DIM, H_DIM);
  gemm_moe<2><<<dim3(H_DIM / 128, 32, E_NUM), 256, 0, stream>>>(
      phi, F_DIM, Wt, b_down, flag, H_DIM, F_DIM, counts, bases, phi, row_token,
      row_weight, out_acc);

  out_convert<<<(N_TOK * H_DIM / 4) / 256, 256, 0, stream>>>(out_acc, flag,
                                                             d_out);
}

// Round 5
// 589.288 us; speedup vs baseline: 1.1234x; 1.1234x over previous
//
#include <hip/hip_runtime.h>
#include <hip/hip_bf16.h>
#include <cstdint>
#include <cstddef>

// B=2,S=2048 -> N=4096 tokens, H=1024, F=2048, E=8, top-2 routing.
// Inputs/outputs fp32 (detected at runtime; bf16 path kept for robustness).
// GEMM compute: bf16 MFMA 16x16x32, fp32 accumulate, BK=64, XOR-swizzled LDS.
#define N_TOK 4096
#define H_DIM 1024
#define F_DIM 2048
#define E_NUM 8
#define RCAP 9216  // 2*N + E*127 rounded up to 128

typedef __attribute__((ext_vector_type(8))) short bf16x8;
typedef __attribute__((ext_vector_type(4))) float f32x4;

__device__ __forceinline__ float b2f(uint16_t u) {
  return __uint_as_float(((uint32_t)u) << 16);
}
__device__ __forceinline__ uint16_t f2b(float f) {
  uint32_t x = __float_as_uint(f);
  uint32_t r = (x + 0x7fffu + ((x >> 16) & 1u)) >> 16;
  return (uint16_t)r;
}

__device__ __forceinline__ void gl2lds16(const void* g, void* l) {
  __builtin_amdgcn_global_load_lds(
      (const __attribute__((address_space(1))) uint32_t*)g,
      (__attribute__((address_space(3))) uint32_t*)l, 16, 0, 0);
}

// Stage a 128x64 bf16 tile (16 KB) into LDS with XOR-swizzled 16B units.
// LDS(R, unit') holds global unit u = unit' ^ (R&7); implemented by choosing
// each lane's *source* address (gl2lds dest is fixed wave-uniform + lane*16).
// src points at tile origin (row r0, col k0), ldK = row stride in elements.
__device__ __forceinline__ void stage_tile(const uint16_t* src, int ldK,
                                           char* lds, int wave, int lane) {
  int u = (lane & 7) ^ (lane >> 3);  // == unit' ^ (R&7)
  const char* s0 = (const char*)src + u * 16;
  size_t rb = (size_t)ldK * 2;
  int Rb = wave * 32 + (lane >> 3);
  for (int c = 0; c < 4; ++c) {
    gl2lds16(s0 + (size_t)(Rb + c * 8) * rb, lds + wave * 4096 + c * 1024);
  }
}

// Read one MFMA fragment (8 bf16 = 16B unit) from a swizzled tile.
__device__ __forceinline__ bf16x8 read_frag(const char* lds, int R, int s,
                                            int q) {
  int unit = ((s << 2) + q) ^ (R & 7);
  return *(const bf16x8*)(lds + R * 128 + unit * 16);
}

// ---------------- input dtype detection ----------------
__global__ __launch_bounds__(256) void detect_kernel(
    const uint16_t* __restrict__ x, int* __restrict__ flag) {
  __shared__ int cnt;
  if (threadIdx.x == 0) cnt = 0;
  __syncthreads();
  int ok = 0;
  for (int j = 0; j < 16; ++j) {
    uint16_t u = x[threadIdx.x * 16 + j];
    int e = (u >> 7) & 0xff;
    ok += (u == 0 || (e >= 96 && e <= 143)) ? 1 : 0;
  }
  atomicAdd(&cnt, ok);
  __syncthreads();
  if (threadIdx.x == 0) *flag = (cnt >= 3700) ? 1 : 0;  // 1 = bf16 inputs
}

// ---------------- router: fp32 logits (native-dtype reads), top-2 ----------
__global__ __launch_bounds__(256) void router_kernel(
    const void* __restrict__ xraw, const void* __restrict__ gwraw,
    const int* __restrict__ flag, void* __restrict__ dout,
    int* __restrict__ top_i, float* __restrict__ top_w,
    int* __restrict__ counts) {
  int fl = *flag;
  int wave = threadIdx.x >> 6, lane = threadIdx.x & 63;
  int t = blockIdx.x * 4 + wave;  // one wave per token
  float xv[16];
  if (fl) {
    const uint16_t* xr = (const uint16_t*)xraw + (size_t)t * H_DIM + lane * 16;
    uint4 a = *(const uint4*)xr;
    uint4 b = *(const uint4*)(xr + 8);
    uint32_t w[8] = {a.x, a.y, a.z, a.w, b.x, b.y, b.z, b.w};
    for (int j = 0; j < 8; ++j) {
      xv[2 * j] = b2f((uint16_t)(w[j] & 0xffff));
      xv[2 * j + 1] = b2f((uint16_t)(w[j] >> 16));
    }
  } else {
    const float* xr = (const float*)xraw + (size_t)t * H_DIM + lane * 16;
    for (int j = 0; j < 4; ++j) {
      float4 v = ((const float4*)xr)[j];
      xv[4 * j] = v.x; xv[4 * j + 1] = v.y;
      xv[4 * j + 2] = v.z; xv[4 * j + 3] = v.w;
    }
  }
  float acc[E_NUM];
  for (int e = 0; e < E_NUM; ++e) {
    float s = 0.f;
    if (fl) {
      const uint16_t* gr =
          (const uint16_t*)gwraw + (size_t)e * H_DIM + lane * 16;
      uint4 a = *(const uint4*)gr;
      uint4 b = *(const uint4*)(gr + 8);
      uint32_t w[8] = {a.x, a.y, a.z, a.w, b.x, b.y, b.z, b.w};
      for (int j = 0; j < 8; ++j) {
        s += xv[2 * j] * b2f((uint16_t)(w[j] & 0xffff));
        s += xv[2 * j + 1] * b2f((uint16_t)(w[j] >> 16));
      }
    } else {
      const float* gr = (const float*)gwraw + (size_t)e * H_DIM + lane * 16;
      for (int j = 0; j < 4; ++j) {
        float4 v = ((const float4*)gr)[j];
        s += xv[4 * j] * v.x + xv[4 * j + 1] * v.y + xv[4 * j + 2] * v.z +
             xv[4 * j + 3] * v.w;
      }
    }
    acc[e] = s;
  }
  for (int off = 32; off >= 1; off >>= 1)
    for (int e = 0; e < E_NUM; ++e)
      acc[e] += __shfl_xor(acc[e], off, 64);
  if (lane < E_NUM) {
    size_t idx = (size_t)N_TOK * H_DIM + (size_t)t * E_NUM + lane;
    if (fl)
      ((uint16_t*)dout)[idx] = f2b(acc[lane]);
    else
      ((float*)dout)[idx] = acc[lane];
  }
  if (lane == 0) {
    int b0 = 0;
    float v0 = acc[0];
    for (int e = 1; e < E_NUM; ++e)
      if (acc[e] > v0) { v0 = acc[e]; b0 = e; }
    int b1 = (b0 == 0) ? 1 : 0;
    float v1 = acc[b1];
    for (int e = 0; e < E_NUM; ++e)
      if (e != b0 && acc[e] > v1) { v1 = acc[e]; b1 = e; }
    float w0 = 1.f / (1.f + expf(v1 - v0));  // top-2 renorm == 2-way softmax
    float w1 = 1.f - w0;
    top_i[2 * t] = b0; top_i[2 * t + 1] = b1;
    top_w[2 * t] = w0; top_w[2 * t + 1] = w1;
    atomicAdd(&counts[b0], 1);
    atomicAdd(&counts[b1], 1);
  }
}

// ---------------- per-expert bases (128-row padded) ----------------
__global__ void offsets_kernel(const int* __restrict__ counts,
                               int* __restrict__ bases, int* __restrict__ cursor) {
  if (threadIdx.x == 0 && blockIdx.x == 0) {
    int b = 0;
    for (int e = 0; e < E_NUM; ++e) {
      bases[e] = b;
      cursor[e] = b;
      b += (counts[e] + 127) & ~127;
    }
  }
}

// ---------------- gather tokens -> contiguous bf16 rows (canonicalize) ------
__global__ __launch_bounds__(256) void gather_kernel(
    const void* __restrict__ xraw, const int* __restrict__ flag,
    const int* __restrict__ top_i, const float* __restrict__ top_w,
    int* __restrict__ cursor, int* __restrict__ row_token,
    float* __restrict__ row_weight, uint16_t* __restrict__ Xg) {
  int t = blockIdx.x;
  __shared__ int rs[2];
  if (threadIdx.x < 2) {
    int e = top_i[2 * t + threadIdx.x];
    int r = atomicAdd(&cursor[e], 1);
    row_token[r] = t;
    row_weight[r] = top_w[2 * t + threadIdx.x];
    rs[threadIdx.x] = r;
  }
  __syncthreads();
  uint2 v;
  if (*flag) {
    v = ((const uint2*)((const uint16_t*)xraw + (size_t)t * H_DIM))[threadIdx.x];
  } else {
    float4 f =
        ((const float4*)((const float*)xraw + (size_t)t * H_DIM))[threadIdx.x];
    v.x = (uint32_t)f2b(f.x) | ((uint32_t)f2b(f.y) << 16);
    v.y = (uint32_t)f2b(f.z) | ((uint32_t)f2b(f.w) << 16);
  }
  ((uint2*)(Xg + (size_t)rs[0] * H_DIM))[threadIdx.x] = v;
  ((uint2*)(Xg + (size_t)rs[1] * H_DIM))[threadIdx.x] = v;
}

// ------------- weight transpose [E][K][N] -> [E][N][K], canonicalize bf16 ---
__global__ __launch_bounds__(256) void transpose_kernel(
    const void* __restrict__ W, const int* __restrict__ flag,
    uint16_t* __restrict__ Wt, int K, int N) {
  int e = blockIdx.z;
  int n0 = blockIdx.x * 64, k0 = blockIdx.y * 64;
  __shared__ __align__(16) uint16_t tile[64][72];
  size_t ebase = (size_t)e * K * N;
  uint16_t* Wout = Wt + ebase;
  int fl = *flag;
  int r = threadIdx.x >> 3;
  int c = (threadIdx.x & 7) * 8;
  if (fl) {
    const uint16_t* Win = (const uint16_t*)W + ebase;
    for (int it = 0; it < 2; ++it) {
      int row = r + it * 32;
      uint4 v = *(const uint4*)(Win + (size_t)(k0 + row) * N + n0 + c);
      *(uint4*)&tile[row][c] = v;
    }
  } else {
    const float* Win = (const float*)W + ebase;
    for (int it = 0; it < 2; ++it) {
      int row = r + it * 32;
      const float* p = Win + (size_t)(k0 + row) * N + n0 + c;
      float4 a = ((const float4*)p)[0];
      float4 b = ((const float4*)p)[1];
      uint16_t* tp = &tile[row][c];
      tp[0] = f2b(a.x); tp[1] = f2b(a.y); tp[2] = f2b(a.z); tp[3] = f2b(a.w);
      tp[4] = f2b(b.x); tp[5] = f2b(b.y); tp[6] = f2b(b.z); tp[7] = f2b(b.w);
    }
  }
  __syncthreads();
  for (int it = 0; it < 2; ++it) {
    int n = r + it * 32;
    uint4 o;
    o.x = (uint32_t)tile[c + 0][n] | ((uint32_t)tile[c + 1][n] << 16);
    o.y = (uint32_t)tile[c + 2][n] | ((uint32_t)tile[c + 3][n] << 16);
    o.z = (uint32_t)tile[c + 4][n] | ((uint32_t)tile[c + 5][n] << 16);
    o.w = (uint32_t)tile[c + 6][n] | ((uint32_t)tile[c + 7][n] << 16);
    *(uint4*)(Wout + (size_t)(n0 + n) * K + k0 + c) = o;
  }
}

// ------------- fused up+gate GEMM: phi = silu(X@Wg+bg) * (X@Wu+bu) ---------
// 128x128 tile, BK=64, 48 KB LDS, dual accumulators, one phi write.
__global__ __launch_bounds__(256, 2) void gemm_upgate(
    const uint16_t* __restrict__ Xg,
    const uint16_t* __restrict__ WtU, const uint16_t* __restrict__ WtG,
    const void* __restrict__ buRaw, const void* __restrict__ bgRaw,
    const int* __restrict__ flag,
    const int* __restrict__ counts, const int* __restrict__ bases,
    uint16_t* __restrict__ phi) {
  int e = blockIdx.z;
  int cnt = counts[e];
  int m0 = blockIdx.y * 128;
  if (m0 >= cnt) return;
  int n0 = blockIdx.x * 128;
  int base = bases[e];
  const uint16_t* A = Xg + (size_t)(base + m0) * H_DIM;
  const uint16_t* BU = WtU + (size_t)e * F_DIM * H_DIM + (size_t)n0 * H_DIM;
  const uint16_t* BG = WtG + (size_t)e * F_DIM * H_DIM + (size_t)n0 * H_DIM;

  __shared__ __align__(16) char lA[128 * 128];   // 128 rows x 64 bf16
  __shared__ __align__(16) char lBu[128 * 128];
  __shared__ __align__(16) char lBg[128 * 128];

  int tid = threadIdx.x;
  int wave = tid >> 6, lane = tid & 63;
  int wm = wave >> 1, wn = wave & 1;
  int q = lane >> 4, mr = lane & 15;

  f32x4 accU[4][4] = {};
  f32x4 accG[4][4] = {};

  for (int k0 = 0; k0 < H_DIM; k0 += 64) {
    __syncthreads();
    stage_tile(A + k0, H_DIM, lA, wave, lane);
    stage_tile(BU + k0, H_DIM, lBu, wave, lane);
    stage_tile(BG + k0, H_DIM, lBg, wave, lane);
    __syncthreads();
    for (int s = 0; s < 2; ++s) {
      bf16x8 af[4], bu[4], bg[4];
      for (int mt = 0; mt < 4; ++mt)
        af[mt] = read_frag(lA, wm * 64 + mt * 16 + mr, s, q);
      for (int nt = 0; nt < 4; ++nt) {
        bu[nt] = read_frag(lBu, wn * 64 + nt * 16 + mr, s, q);
        bg[nt] = read_frag(lBg, wn * 64 + nt * 16 + mr, s, q);
      }
      for (int mt = 0; mt < 4; ++mt)
        for (int nt = 0; nt < 4; ++nt) {
          accU[mt][nt] = __builtin_amdgcn_mfma_f32_16x16x32_bf16(
              af[mt], bu[nt], accU[mt][nt], 0, 0, 0);
          accG[mt][nt] = __builtin_amdgcn_mfma_f32_16x16x32_bf16(
              af[mt], bg[nt], accG[mt][nt], 0, 0, 0);
        }
    }
  }

  // C/D: col = lane&15, row = (lane>>4)*4 + reg
  int fl = *flag;
  int rbase = m0 + wm * 64;
  int cbase = n0 + wn * 64;
  for (int nt = 0; nt < 4; ++nt) {
    int col = cbase + nt * 16 + mr;
    float bu_v, bg_v;
    if (fl) {
      bu_v = b2f(((const uint16_t*)buRaw)[(size_t)e * F_DIM + col]);
      bg_v = b2f(((const uint16_t*)bgRaw)[(size_t)e * F_DIM + col]);
    } else {
      bu_v = ((const float*)buRaw)[(size_t)e * F_DIM + col];
      bg_v = ((const float*)bgRaw)[(size_t)e * F_DIM + col];
    }
    for (int mt = 0; mt < 4; ++mt) {
      int r0 = rbase + mt * 16 + q * 4;
      for (int rg = 0; rg < 4; ++rg) {
        int row = r0 + rg;
        float u = accU[mt][nt][rg] + bu_v;
        float v = accG[mt][nt][rg] + bg_v;
        float s = v / (1.f + expf(-v));  // silu
        phi[(size_t)(base + row) * F_DIM + col] = f2b(s * u);
      }
    }
  }
}

// ------------- down GEMM + combine: out_acc[tok] += w*(phi@Wd + bd) --------
__global__ __launch_bounds__(256, 2) void gemm_down(
    const uint16_t* __restrict__ phi, const uint16_t* __restrict__ WtD,
    const void* __restrict__ bdRaw, const int* __restrict__ flag,
    const int* __restrict__ counts, const int* __restrict__ bases,
    const int* __restrict__ row_token, const float* __restrict__ row_weight,
    float* __restrict__ out_acc) {
  int e = blockIdx.z;
  int cnt = counts[e];
  int m0 = blockIdx.y * 128;
  if (m0 >= cnt) return;
  int n0 = blockIdx.x * 128;
  int base = bases[e];
  const uint16_t* A = phi + (size_t)(base + m0) * F_DIM;
  const uint16_t* B = WtD + (size_t)e * H_DIM * F_DIM + (size_t)n0 * F_DIM;

  __shared__ __align__(16) char lA[128 * 128];
  __shared__ __align__(16) char lB[128 * 128];

  int tid = threadIdx.x;
  int wave = tid >> 6, lane = tid & 63;
  int wm = wave >> 1, wn = wave & 1;
  int q = lane >> 4, mr = lane & 15;

  f32x4 acc[4][4] = {};

  for (int k0 = 0; k0 < F_DIM; k0 += 64) {
    __syncthreads();
    stage_tile(A + k0, F_DIM, lA, wave, lane);
    stage_tile(B + k0, F_DIM, lB, wave, lane);
    __syncthreads();
    for (int s = 0; s < 2; ++s) {
      bf16x8 af[4], bf[4];
      for (int mt = 0; mt < 4; ++mt)
        af[mt] = read_frag(lA, wm * 64 + mt * 16 + mr, s, q);
      for (int nt = 0; nt < 4; ++nt)
        bf[nt] = read_frag(lB, wn * 64 + nt * 16 + mr, s, q);
      for (int mt = 0; mt < 4; ++mt)
        for (int nt = 0; nt < 4; ++nt)
          acc[mt][nt] = __builtin_amdgcn_mfma_f32_16x16x32_bf16(
              af[mt], bf[nt], acc[mt][nt], 0, 0, 0);
    }
  }

  int fl = *flag;
  int rbase = m0 + wm * 64;
  int cbase = n0 + wn * 64;
  for (int nt = 0; nt < 4; ++nt) {
    int col = cbase + nt * 16 + mr;
    float bd_v = fl ? b2f(((const uint16_t*)bdRaw)[(size_t)e * H_DIM + col])
                    : ((const float*)bdRaw)[(size_t)e * H_DIM + col];
    for (int mt = 0; mt < 4; ++mt) {
      int r0 = rbase + mt * 16 + q * 4;
      for (int rg = 0; rg < 4; ++rg) {
        int row = r0 + rg;
        if (row < cnt) {
          int tkn = row_token[base + row];
          float w = row_weight[base + row];
          atomicAdd(out_acc + (size_t)tkn * H_DIM + col,
                    w * (acc[mt][nt][rg] + bd_v));
        }
      }
    }
  }
}

// ---------------- fp32 accumulator -> output (dtype per flag) ---------------
__global__ __launch_bounds__(256) void out_convert(
    const float* __restrict__ acc, const int* __restrict__ flag,
    void* __restrict__ out) {
  int i = blockIdx.x * 256 + threadIdx.x;
  float4 v = ((const float4*)acc)[i];
  if (*flag) {
    uint2 o;
    o.x = (uint32_t)f2b(v.x) | ((uint32_t)f2b(v.y) << 16);
    o.y = (uint32_t)f2b(v.z) | ((uint32_t)f2b(v.w) << 16);
    ((uint2*)out)[i] = o;
  } else {
    ((float4*)out)[i] = v;
  }
}

extern "C" void kernel_launch(void* const* d_in, const int* in_sizes, int n_in,
                              void* d_out, int out_size, void* d_ws, size_t ws_size,
                              hipStream_t stream) {
  const void* x = d_in[0];
  const void* gw = d_in[1];
  const void* w_up = d_in[2];
  const void* w_gate = d_in[3];
  const void* w_down = d_in[4];
  const void* b_up = d_in[5];
  const void* b_gate = d_in[6];
  const void* b_down = d_in[7];

  // ws layout (~139 MB)
  char* ws = (char*)d_ws;
  size_t off = 0;
  auto alloc = [&](size_t bytes) -> void* {
    void* p = ws + off;
    off += (bytes + 255) & ~(size_t)255;
    return p;
  };
  int* counts = (int*)alloc(32);
  int* bases = (int*)alloc(32);
  int* cursor = (int*)alloc(32);
  int* flag = (int*)alloc(32);
  int* top_i = (int*)alloc(sizeof(int) * N_TOK * 2);
  float* top_w = (float*)alloc(sizeof(float) * N_TOK * 2);
  int* row_token = (int*)alloc(sizeof(int) * RCAP);
  float* row_weight = (float*)alloc(sizeof(float) * RCAP);
  uint16_t* Xg = (uint16_t*)alloc((size_t)RCAP * H_DIM * 2);
  uint16_t* phi = (uint16_t*)alloc((size_t)RCAP * F_DIM * 2);
  uint16_t* WtU = (uint16_t*)alloc((size_t)E_NUM * H_DIM * F_DIM * 2);
  uint16_t* WtG = (uint16_t*)alloc((size_t)E_NUM * H_DIM * F_DIM * 2);
  float* out_acc = (float*)alloc((size_t)N_TOK * H_DIM * sizeof(float));

  hipMemsetAsync(counts, 0, 32, stream);
  hipMemsetAsync(out_acc, 0, (size_t)N_TOK * H_DIM * sizeof(float), stream);

  detect_kernel<<<1, 256, 0, stream>>>((const uint16_t*)x, flag);
  router_kernel<<<N_TOK / 4, 256, 0, stream>>>(x, gw, flag, d_out, top_i,
                                               top_w, counts);
  offsets_kernel<<<1, 64, 0, stream>>>(counts, bases, cursor);
  gather_kernel<<<N_TOK, 256, 0, stream>>>(x, flag, top_i, top_w, cursor,
                                           row_token, row_weight, Xg);

  // transposes: up -> WtU, gate -> WtG (both alive for the fused GEMM)
  transpose_kernel<<<dim3(F_DIM / 64, H_DIM / 64, E_NUM), 256, 0, stream>>>(
      w_up, flag, WtU, H_DIM, F_DIM);
  transpose_kernel<<<dim3(F_DIM / 64, H_DIM / 64, E_NUM), 256, 0, stream>>>(
      w_gate, flag, WtG, H_DIM, F_DIM);

  gemm_upgate<<<dim3(F_DIM / 128, 32, E_NUM), 256, 0, stream>>>(
      Xg, WtU, WtG, b_up, b_gate, flag, counts, bases, phi);

  // down transpose reuses WtU (free after fused GEMM)
  transpose_kernel<<<dim3(H_DIM / 64, F_DIM / 64, E_NUM), 256, 0, stream>>>(
      w_down, flag, WtU, F_DIM, H_DIM);
  gemm_down<<<dim3(H_DIM / 128, 32, E_NUM), 256, 0, stream>>>(
      phi, WtU, b_down, flag, counts, bases, row_token, row_weight, out_acc);

  out_convert<<<(N_TOK * H_DIM / 4) / 256, 256, 0, stream>>>(out_acc, flag,
                                                             d_out);
}

// Round 6
// 461.379 us; speedup vs baseline: 1.4349x; 1.2772x over previous
//
#include <hip/hip_runtime.h>
#include <hip/hip_bf16.h>
#include <cstdint>
#include <cstddef>

// B=2,S=2048 -> N=4096 tokens, H=1024, F=2048, E=8, top-2 routing.
// Inputs/outputs fp32 (detected at runtime; bf16 path kept for robustness).
// GEMM compute: bf16 MFMA 16x16x32, fp32 accumulate, BK=64, XOR-swizzled LDS.
// R6: atomic-free routing scaffold (shfl/LDS scan instead of same-line atomics).
#define N_TOK 4096
#define H_DIM 1024
#define F_DIM 2048
#define E_NUM 8
#define RCAP 9216  // 2*N + E*127 rounded up to 128

typedef __attribute__((ext_vector_type(8))) short bf16x8;
typedef __attribute__((ext_vector_type(4))) float f32x4;

__device__ __forceinline__ float b2f(uint16_t u) {
  return __uint_as_float(((uint32_t)u) << 16);
}
__device__ __forceinline__ uint16_t f2b(float f) {
  uint32_t x = __float_as_uint(f);
  uint32_t r = (x + 0x7fffu + ((x >> 16) & 1u)) >> 16;
  return (uint16_t)r;
}

__device__ __forceinline__ void gl2lds16(const void* g, void* l) {
  __builtin_amdgcn_global_load_lds(
      (const __attribute__((address_space(1))) uint32_t*)g,
      (__attribute__((address_space(3))) uint32_t*)l, 16, 0, 0);
}

// Stage a 128x64 bf16 tile (16 KB) into LDS with XOR-swizzled 16B units.
__device__ __forceinline__ void stage_tile(const uint16_t* src, int ldK,
                                           char* lds, int wave, int lane) {
  int u = (lane & 7) ^ (lane >> 3);
  const char* s0 = (const char*)src + u * 16;
  size_t rb = (size_t)ldK * 2;
  int Rb = wave * 32 + (lane >> 3);
  for (int c = 0; c < 4; ++c) {
    gl2lds16(s0 + (size_t)(Rb + c * 8) * rb, lds + wave * 4096 + c * 1024);
  }
}

__device__ __forceinline__ bf16x8 read_frag(const char* lds, int R, int s,
                                            int q) {
  int unit = ((s << 2) + q) ^ (R & 7);
  return *(const bf16x8*)(lds + R * 128 + unit * 16);
}

// ---------------- input dtype detection ----------------
__global__ __launch_bounds__(256) void detect_kernel(
    const uint16_t* __restrict__ x, int* __restrict__ flag) {
  __shared__ int cnt;
  if (threadIdx.x == 0) cnt = 0;
  __syncthreads();
  int ok = 0;
  for (int j = 0; j < 16; ++j) {
    uint16_t u = x[threadIdx.x * 16 + j];
    int e = (u >> 7) & 0xff;
    ok += (u == 0 || (e >= 96 && e <= 143)) ? 1 : 0;
  }
  atomicAdd(&cnt, ok);
  __syncthreads();
  if (threadIdx.x == 0) *flag = (cnt >= 3700) ? 1 : 0;  // 1 = bf16 inputs
}

// ---------------- router: fp32 logits, top-2 (NO atomics) ----------
__global__ __launch_bounds__(256) void router_kernel(
    const void* __restrict__ xraw, const void* __restrict__ gwraw,
    const int* __restrict__ flag, void* __restrict__ dout,
    int* __restrict__ top_i, float* __restrict__ top_w) {
  int fl = *flag;
  int wave = threadIdx.x >> 6, lane = threadIdx.x & 63;
  int t = blockIdx.x * 4 + wave;  // one wave per token
  float xv[16];
  if (fl) {
    const uint16_t* xr = (const uint16_t*)xraw + (size_t)t * H_DIM + lane * 16;
    uint4 a = *(const uint4*)xr;
    uint4 b = *(const uint4*)(xr + 8);
    uint32_t w[8] = {a.x, a.y, a.z, a.w, b.x, b.y, b.z, b.w};
    for (int j = 0; j < 8; ++j) {
      xv[2 * j] = b2f((uint16_t)(w[j] & 0xffff));
      xv[2 * j + 1] = b2f((uint16_t)(w[j] >> 16));
    }
  } else {
    const float* xr = (const float*)xraw + (size_t)t * H_DIM + lane * 16;
    for (int j = 0; j < 4; ++j) {
      float4 v = ((const float4*)xr)[j];
      xv[4 * j] = v.x; xv[4 * j + 1] = v.y;
      xv[4 * j + 2] = v.z; xv[4 * j + 3] = v.w;
    }
  }
  float acc[E_NUM];
  for (int e = 0; e < E_NUM; ++e) {
    float s = 0.f;
    if (fl) {
      const uint16_t* gr =
          (const uint16_t*)gwraw + (size_t)e * H_DIM + lane * 16;
      uint4 a = *(const uint4*)gr;
      uint4 b = *(const uint4*)(gr + 8);
      uint32_t w[8] = {a.x, a.y, a.z, a.w, b.x, b.y, b.z, b.w};
      for (int j = 0; j < 8; ++j) {
        s += xv[2 * j] * b2f((uint16_t)(w[j] & 0xffff));
        s += xv[2 * j + 1] * b2f((uint16_t)(w[j] >> 16));
      }
    } else {
      const float* gr = (const float*)gwraw + (size_t)e * H_DIM + lane * 16;
      for (int j = 0; j < 4; ++j) {
        float4 v = ((const float4*)gr)[j];
        s += xv[4 * j] * v.x + xv[4 * j + 1] * v.y + xv[4 * j + 2] * v.z +
             xv[4 * j + 3] * v.w;
      }
    }
    acc[e] = s;
  }
  for (int off = 32; off >= 1; off >>= 1)
    for (int e = 0; e < E_NUM; ++e)
      acc[e] += __shfl_xor(acc[e], off, 64);
  if (lane < E_NUM) {
    size_t idx = (size_t)N_TOK * H_DIM + (size_t)t * E_NUM + lane;
    if (fl)
      ((uint16_t*)dout)[idx] = f2b(acc[lane]);
    else
      ((float*)dout)[idx] = acc[lane];
  }
  if (lane == 0) {
    int b0 = 0;
    float v0 = acc[0];
    for (int e = 1; e < E_NUM; ++e)
      if (acc[e] > v0) { v0 = acc[e]; b0 = e; }
    int b1 = (b0 == 0) ? 1 : 0;
    float v1 = acc[b1];
    for (int e = 0; e < E_NUM; ++e)
      if (e != b0 && acc[e] > v1) { v1 = acc[e]; b1 = e; }
    float w0 = 1.f / (1.f + expf(v1 - v0));  // top-2 renorm == 2-way softmax
    top_i[2 * t] = b0; top_i[2 * t + 1] = b1;
    top_w[2 * t] = w0; top_w[2 * t + 1] = 1.f - w0;
  }
}

// ------- histogram + scan + row assignment (1 block, zero contention) ------
// Each thread owns 8 consecutive (token,slot) entries; register histogram ->
// per-wave shfl_up inclusive scan -> LDS cross-wave scan -> unique rows.
__global__ __launch_bounds__(1024) void histscan_kernel(
    const int* __restrict__ top_i, const float* __restrict__ top_w,
    int* __restrict__ counts, int* __restrict__ bases,
    int* __restrict__ row_of, int* __restrict__ row_token,
    float* __restrict__ row_weight) {
  int tid = threadIdx.x;           // 0..1023
  int lane = tid & 63, wave = tid >> 6;  // 16 waves
  int e_loc[8];
  float tw[8];
  int c[E_NUM] = {};
  for (int j = 0; j < 8; ++j) {
    int idx = tid * 8 + j;
    int e = top_i[idx];
    e_loc[j] = e;
    tw[j] = top_w[idx];
    c[e]++;
  }
  int inc[E_NUM];
  for (int k = 0; k < E_NUM; ++k) inc[k] = c[k];
  for (int off = 1; off < 64; off <<= 1) {
    for (int k = 0; k < E_NUM; ++k) {
      int v = __shfl_up(inc[k], off, 64);
      if (lane >= off) inc[k] += v;
    }
  }
  __shared__ int wtot[16][E_NUM];
  __shared__ int woff[16][E_NUM];
  __shared__ int base_s[E_NUM];
  if (lane == 63)
    for (int k = 0; k < E_NUM; ++k) wtot[wave][k] = inc[k];
  __syncthreads();
  if (tid < E_NUM) {  // thread k scans expert k across waves
    int run = 0;
    for (int w = 0; w < 16; ++w) {
      woff[w][tid] = run;
      run += wtot[w][tid];
    }
    counts[tid] = run;
    wtot[0][tid] = run;  // reuse as totals
  }
  __syncthreads();
  if (tid == 0) {
    int b = 0;
    for (int e = 0; e < E_NUM; ++e) {
      bases[e] = b;
      base_s[e] = b;
      b += (wtot[0][e] + 127) & ~127;
    }
  }
  __syncthreads();
  int run[E_NUM];
  for (int k = 0; k < E_NUM; ++k)
    run[k] = base_s[k] + woff[wave][k] + inc[k] - c[k];  // exclusive prefix
  for (int j = 0; j < 8; ++j) {
    int idx = tid * 8 + j;
    int e = e_loc[j];
    int r = run[e]++;
    row_of[idx] = r;
    row_token[r] = idx >> 1;
    row_weight[r] = tw[j];
  }
}

// ---------------- gather tokens -> contiguous bf16 rows (no atomics) -------
__global__ __launch_bounds__(256) void gather_kernel(
    const void* __restrict__ xraw, const int* __restrict__ flag,
    const int* __restrict__ row_of, uint16_t* __restrict__ Xg) {
  int t = blockIdx.x;
  int rs0 = row_of[2 * t], rs1 = row_of[2 * t + 1];
  uint2 v;
  if (*flag) {
    v = ((const uint2*)((const uint16_t*)xraw + (size_t)t * H_DIM))[threadIdx.x];
  } else {
    float4 f =
        ((const float4*)((const float*)xraw + (size_t)t * H_DIM))[threadIdx.x];
    v.x = (uint32_t)f2b(f.x) | ((uint32_t)f2b(f.y) << 16);
    v.y = (uint32_t)f2b(f.z) | ((uint32_t)f2b(f.w) << 16);
  }
  ((uint2*)(Xg + (size_t)rs0 * H_DIM))[threadIdx.x] = v;
  ((uint2*)(Xg + (size_t)rs1 * H_DIM))[threadIdx.x] = v;
}

// ------------- weight transpose [E][K][N] -> [E][N][K], canonicalize bf16 ---
__global__ __launch_bounds__(256) void transpose_kernel(
    const void* __restrict__ W, const int* __restrict__ flag,
    uint16_t* __restrict__ Wt, int K, int N) {
  int e = blockIdx.z;
  int n0 = blockIdx.x * 64, k0 = blockIdx.y * 64;
  __shared__ __align__(16) uint16_t tile[64][72];
  size_t ebase = (size_t)e * K * N;
  uint16_t* Wout = Wt + ebase;
  int fl = *flag;
  int r = threadIdx.x >> 3;
  int c = (threadIdx.x & 7) * 8;
  if (fl) {
    const uint16_t* Win = (const uint16_t*)W + ebase;
    for (int it = 0; it < 2; ++it) {
      int row = r + it * 32;
      uint4 v = *(const uint4*)(Win + (size_t)(k0 + row) * N + n0 + c);
      *(uint4*)&tile[row][c] = v;
    }
  } else {
    const float* Win = (const float*)W + ebase;
    for (int it = 0; it < 2; ++it) {
      int row = r + it * 32;
      const float* p = Win + (size_t)(k0 + row) * N + n0 + c;
      float4 a = ((const float4*)p)[0];
      float4 b = ((const float4*)p)[1];
      uint16_t* tp = &tile[row][c];
      tp[0] = f2b(a.x); tp[1] = f2b(a.y); tp[2] = f2b(a.z); tp[3] = f2b(a.w);
      tp[4] = f2b(b.x); tp[5] = f2b(b.y); tp[6] = f2b(b.z); tp[7] = f2b(b.w);
    }
  }
  __syncthreads();
  for (int it = 0; it < 2; ++it) {
    int n = r + it * 32;
    uint4 o;
    o.x = (uint32_t)tile[c + 0][n] | ((uint32_t)tile[c + 1][n] << 16);
    o.y = (uint32_t)tile[c + 2][n] | ((uint32_t)tile[c + 3][n] << 16);
    o.z = (uint32_t)tile[c + 4][n] | ((uint32_t)tile[c + 5][n] << 16);
    o.w = (uint32_t)tile[c + 6][n] | ((uint32_t)tile[c + 7][n] << 16);
    *(uint4*)(Wout + (size_t)(n0 + n) * K + k0 + c) = o;
  }
}

// ------------- fused up+gate GEMM: phi = silu(X@Wg+bg) * (X@Wu+bu) ---------
__global__ __launch_bounds__(256, 2) void gemm_upgate(
    const uint16_t* __restrict__ Xg,
    const uint16_t* __restrict__ WtU, const uint16_t* __restrict__ WtG,
    const void* __restrict__ buRaw, const void* __restrict__ bgRaw,
    const int* __restrict__ flag,
    const int* __restrict__ counts, const int* __restrict__ bases,
    uint16_t* __restrict__ phi) {
  int e = blockIdx.z;
  int cnt = counts[e];
  int m0 = blockIdx.y * 128;
  if (m0 >= cnt) return;
  int n0 = blockIdx.x * 128;
  int base = bases[e];
  const uint16_t* A = Xg + (size_t)(base + m0) * H_DIM;
  const uint16_t* BU = WtU + (size_t)e * F_DIM * H_DIM + (size_t)n0 * H_DIM;
  const uint16_t* BG = WtG + (size_t)e * F_DIM * H_DIM + (size_t)n0 * H_DIM;

  __shared__ __align__(16) char lA[128 * 128];
  __shared__ __align__(16) char lBu[128 * 128];
  __shared__ __align__(16) char lBg[128 * 128];

  int tid = threadIdx.x;
  int wave = tid >> 6, lane = tid & 63;
  int wm = wave >> 1, wn = wave & 1;
  int q = lane >> 4, mr = lane & 15;

  f32x4 accU[4][4] = {};
  f32x4 accG[4][4] = {};

  for (int k0 = 0; k0 < H_DIM; k0 += 64) {
    __syncthreads();
    stage_tile(A + k0, H_DIM, lA, wave, lane);
    stage_tile(BU + k0, H_DIM, lBu, wave, lane);
    stage_tile(BG + k0, H_DIM, lBg, wave, lane);
    __syncthreads();
    for (int s = 0; s < 2; ++s) {
      bf16x8 af[4], bu[4], bg[4];
      for (int mt = 0; mt < 4; ++mt)
        af[mt] = read_frag(lA, wm * 64 + mt * 16 + mr, s, q);
      for (int nt = 0; nt < 4; ++nt) {
        bu[nt] = read_frag(lBu, wn * 64 + nt * 16 + mr, s, q);
        bg[nt] = read_frag(lBg, wn * 64 + nt * 16 + mr, s, q);
      }
      for (int mt = 0; mt < 4; ++mt)
        for (int nt = 0; nt < 4; ++nt) {
          accU[mt][nt] = __builtin_amdgcn_mfma_f32_16x16x32_bf16(
              af[mt], bu[nt], accU[mt][nt], 0, 0, 0);
          accG[mt][nt] = __builtin_amdgcn_mfma_f32_16x16x32_bf16(
              af[mt], bg[nt], accG[mt][nt], 0, 0, 0);
        }
    }
  }

  int fl = *flag;
  int rbase = m0 + wm * 64;
  int cbase = n0 + wn * 64;
  for (int nt = 0; nt < 4; ++nt) {
    int col = cbase + nt * 16 + mr;
    float bu_v, bg_v;
    if (fl) {
      bu_v = b2f(((const uint16_t*)buRaw)[(size_t)e * F_DIM + col]);
      bg_v = b2f(((const uint16_t*)bgRaw)[(size_t)e * F_DIM + col]);
    } else {
      bu_v = ((const float*)buRaw)[(size_t)e * F_DIM + col];
      bg_v = ((const float*)bgRaw)[(size_t)e * F_DIM + col];
    }
    for (int mt = 0; mt < 4; ++mt) {
      int r0 = rbase + mt * 16 + q * 4;
      for (int rg = 0; rg < 4; ++rg) {
        int row = r0 + rg;
        float u = accU[mt][nt][rg] + bu_v;
        float v = accG[mt][nt][rg] + bg_v;
        float s = v / (1.f + expf(-v));  // silu
        phi[(size_t)(base + row) * F_DIM + col] = f2b(s * u);
      }
    }
  }
}

// ------------- down GEMM + combine: out_acc[tok] += w*(phi@Wd + bd) --------
__global__ __launch_bounds__(256, 2) void gemm_down(
    const uint16_t* __restrict__ phi, const uint16_t* __restrict__ WtD,
    const void* __restrict__ bdRaw, const int* __restrict__ flag,
    const int* __restrict__ counts, const int* __restrict__ bases,
    const int* __restrict__ row_token, const float* __restrict__ row_weight,
    float* __restrict__ out_acc) {
  int e = blockIdx.z;
  int cnt = counts[e];
  int m0 = blockIdx.y * 128;
  if (m0 >= cnt) return;
  int n0 = blockIdx.x * 128;
  int base = bases[e];
  const uint16_t* A = phi + (size_t)(base + m0) * F_DIM;
  const uint16_t* B = WtD + (size_t)e * H_DIM * F_DIM + (size_t)n0 * F_DIM;

  __shared__ __align__(16) char lA[128 * 128];
  __shared__ __align__(16) char lB[128 * 128];

  int tid = threadIdx.x;
  int wave = tid >> 6, lane = tid & 63;
  int wm = wave >> 1, wn = wave & 1;
  int q = lane >> 4, mr = lane & 15;

  f32x4 acc[4][4] = {};

  for (int k0 = 0; k0 < F_DIM; k0 += 64) {
    __syncthreads();
    stage_tile(A + k0, F_DIM, lA, wave, lane);
    stage_tile(B + k0, F_DIM, lB, wave, lane);
    __syncthreads();
    for (int s = 0; s < 2; ++s) {
      bf16x8 af[4], bf[4];
      for (int mt = 0; mt < 4; ++mt)
        af[mt] = read_frag(lA, wm * 64 + mt * 16 + mr, s, q);
      for (int nt = 0; nt < 4; ++nt)
        bf[nt] = read_frag(lB, wn * 64 + nt * 16 + mr, s, q);
      for (int mt = 0; mt < 4; ++mt)
        for (int nt = 0; nt < 4; ++nt)
          acc[mt][nt] = __builtin_amdgcn_mfma_f32_16x16x32_bf16(
              af[mt], bf[nt], acc[mt][nt], 0, 0, 0);
    }
  }

  int fl = *flag;
  int rbase = m0 + wm * 64;
  int cbase = n0 + wn * 64;
  for (int nt = 0; nt < 4; ++nt) {
    int col = cbase + nt * 16 + mr;
    float bd_v = fl ? b2f(((const uint16_t*)bdRaw)[(size_t)e * H_DIM + col])
                    : ((const float*)bdRaw)[(size_t)e * H_DIM + col];
    for (int mt = 0; mt < 4; ++mt) {
      int r0 = rbase + mt * 16 + q * 4;
      for (int rg = 0; rg < 4; ++rg) {
        int row = r0 + rg;
        if (row < cnt) {
          int tkn = row_token[base + row];
          float w = row_weight[base + row];
          atomicAdd(out_acc + (size_t)tkn * H_DIM + col,
                    w * (acc[mt][nt][rg] + bd_v));
        }
      }
    }
  }
}

// ---------------- fp32 accumulator -> output (dtype per flag) ---------------
__global__ __launch_bounds__(256) void out_convert(
    const float* __restrict__ acc, const int* __restrict__ flag,
    void* __restrict__ out) {
  int i = blockIdx.x * 256 + threadIdx.x;
  float4 v = ((const float4*)acc)[i];
  if (*flag) {
    uint2 o;
    o.x = (uint32_t)f2b(v.x) | ((uint32_t)f2b(v.y) << 16);
    o.y = (uint32_t)f2b(v.z) | ((uint32_t)f2b(v.w) << 16);
    ((uint2*)out)[i] = o;
  } else {
    ((float4*)out)[i] = v;
  }
}

extern "C" void kernel_launch(void* const* d_in, const int* in_sizes, int n_in,
                              void* d_out, int out_size, void* d_ws, size_t ws_size,
                              hipStream_t stream) {
  const void* x = d_in[0];
  const void* gw = d_in[1];
  const void* w_up = d_in[2];
  const void* w_gate = d_in[3];
  const void* w_down = d_in[4];
  const void* b_up = d_in[5];
  const void* b_gate = d_in[6];
  const void* b_down = d_in[7];

  char* ws = (char*)d_ws;
  size_t off = 0;
  auto alloc = [&](size_t bytes) -> void* {
    void* p = ws + off;
    off += (bytes + 255) & ~(size_t)255;
    return p;
  };
  int* counts = (int*)alloc(32);
  int* bases = (int*)alloc(32);
  int* flag = (int*)alloc(32);
  int* top_i = (int*)alloc(sizeof(int) * N_TOK * 2);
  float* top_w = (float*)alloc(sizeof(float) * N_TOK * 2);
  int* row_of = (int*)alloc(sizeof(int) * N_TOK * 2);
  int* row_token = (int*)alloc(sizeof(int) * RCAP);
  float* row_weight = (float*)alloc(sizeof(float) * RCAP);
  uint16_t* Xg = (uint16_t*)alloc((size_t)RCAP * H_DIM * 2);
  uint16_t* phi = (uint16_t*)alloc((size_t)RCAP * F_DIM * 2);
  uint16_t* WtU = (uint16_t*)alloc((size_t)E_NUM * H_DIM * F_DIM * 2);
  uint16_t* WtG = (uint16_t*)alloc((size_t)E_NUM * H_DIM * F_DIM * 2);
  float* out_acc = (float*)alloc((size_t)N_TOK * H_DIM * sizeof(float));

  hipMemsetAsync(out_acc, 0, (size_t)N_TOK * H_DIM * sizeof(float), stream);

  detect_kernel<<<1, 256, 0, stream>>>((const uint16_t*)x, flag);
  router_kernel<<<N_TOK / 4, 256, 0, stream>>>(x, gw, flag, d_out, top_i,
                                               top_w);
  histscan_kernel<<<1, 1024, 0, stream>>>(top_i, top_w, counts, bases, row_of,
                                          row_token, row_weight);
  gather_kernel<<<N_TOK, 256, 0, stream>>>(x, flag, row_of, Xg);

  transpose_kernel<<<dim3(F_DIM / 64, H_DIM / 64, E_NUM), 256, 0, stream>>>(
      w_up, flag, WtU, H_DIM, F_DIM);
  transpose_kernel<<<dim3(F_DIM / 64, H_DIM / 64, E_NUM), 256, 0, stream>>>(
      w_gate, flag, WtG, H_DIM, F_DIM);

  gemm_upgate<<<dim3(F_DIM / 128, 32, E_NUM), 256, 0, stream>>>(
      Xg, WtU, WtG, b_up, b_gate, flag, counts, bases, phi);

  transpose_kernel<<<dim3(H_DIM / 64, F_DIM / 64, E_NUM), 256, 0, stream>>>(
      w_down, flag, WtU, F_DIM, H_DIM);
  gemm_down<<<dim3(H_DIM / 128, 32, E_NUM), 256, 0, stream>>>(
      phi, WtU, b_down, flag, counts, bases, row_token, row_weight, out_acc);

  out_convert<<<(N_TOK * H_DIM / 4) / 256, 256, 0, stream>>>(out_acc, flag,
                                                             d_out);
}